// Round 1
// baseline (538.373 us; speedup 1.0000x reference)
//
#include <hip/hip_runtime.h>

typedef unsigned short u16;
typedef u16 u16x8 __attribute__((ext_vector_type(8)));
typedef __bf16 bf16x8 __attribute__((ext_vector_type(8)));
typedef float f32x4 __attribute__((ext_vector_type(4)));

#define GL2LDS(gp, lp)                                                          \
  __builtin_amdgcn_global_load_lds(                                             \
      (const __attribute__((address_space(1))) void*)(gp),                      \
      (__attribute__((address_space(3))) void*)(lp), 16, 0, 0)

__device__ __forceinline__ u16 f2bf(float f) {
  unsigned u = __builtin_bit_cast(unsigned, f);
  u += 0x7fffu + ((u >> 16) & 1u);
  return (u16)(u >> 16);
}

__device__ __forceinline__ f32x4 mfma_bf16(u16x8 a, u16x8 b, f32x4 c) {
  return __builtin_amdgcn_mfma_f32_16x16x32_bf16(
      __builtin_bit_cast(bf16x8, a), __builtin_bit_cast(bf16x8, b), c, 0, 0, 0);
}

constexpr int BN_ = 8;      // batch
constexpr int S_ = 2048;    // seq
constexpr int D_ = 1024;    // embed

// ---------------------------------------------------------------- convert f32 -> bf16
__global__ __launch_bounds__(256) void cvt_bf16(const float* __restrict__ in,
                                                u16* __restrict__ out, int n8) {
  int i = blockIdx.x * blockDim.x + threadIdx.x;
  int stride = gridDim.x * blockDim.x;
  for (; i < n8; i += stride) {
    const float4* p = reinterpret_cast<const float4*>(in) + (size_t)i * 2;
    float4 a = p[0], b = p[1];
    u16x8 o;
    o[0] = f2bf(a.x); o[1] = f2bf(a.y); o[2] = f2bf(a.z); o[3] = f2bf(a.w);
    o[4] = f2bf(b.x); o[5] = f2bf(b.y); o[6] = f2bf(b.z); o[7] = f2bf(b.w);
    reinterpret_cast<u16x8*>(out)[i] = o;
  }
}

// ---------------------------------------------------------------- mask row inv-norms
// rinv[r] = 1 / max(sum(rot[r,:]^2), EPS^2)   (EPS = 1e-12)
__global__ __launch_bounds__(256) void rownorm_kernel(const float* __restrict__ rot,
                                                      float* __restrict__ rinv) {
  int r = blockIdx.x, t = threadIdx.x;
  const float4* p = reinterpret_cast<const float4*>(rot + (size_t)r * S_);
  float4 a = p[t], b = p[t + 256];
  float s = a.x * a.x + a.y * a.y + a.z * a.z + a.w * a.w +
            b.x * b.x + b.y * b.y + b.z * b.z + b.w * b.w;
#pragma unroll
  for (int d = 1; d < 64; d <<= 1) s += __shfl_xor(s, d);
  __shared__ float wsum[4];
  if ((t & 63) == 0) wsum[t >> 6] = s;
  __syncthreads();
  if (t == 0) {
    float ss = wsum[0] + wsum[1] + wsum[2] + wsum[3];
    rinv[r] = 1.0f / fmaxf(ss, 1e-24f);
  }
}

// ---------------------------------------------------------------- GEMM  C = A @ B^T
// A: M x K bf16 row-major; Bm: N x K bf16 row-major (K contiguous both).
// MODE 0: out bf16 [r*N+c] = acc + bias[c]                (q, k projections)
// MODE 1: out bf16 transposed per batch: vt[b][c][s]      (v projection)
// MODE 2: out fp32 [z][r*N+c] = acc / Z[z][r]             (PV, batched via blockIdx.z)
template <int MODE>
__global__ __launch_bounds__(256)
void gemm_bt(const u16* __restrict__ A, const u16* __restrict__ Bm,
             const float* __restrict__ aux, void* __restrict__ outp,
             int M, int N, int K) {
  __shared__ alignas(16) u16 As[4096];
  __shared__ alignas(16) u16 Bs[4096];
  const int t = threadIdx.x;
  const int lane = t & 63, w = t >> 6;
  const int wm = w >> 1, wn = w & 1;
  const int z = blockIdx.z;

  const u16* Ab = A + (MODE == 2 ? (size_t)z * S_ * S_ : 0);
  const u16* Bb = Bm + (MODE == 2 ? (size_t)z * D_ * S_ : 0);

  const int rowBase = blockIdx.y * 128;
  const int colBase = blockIdx.x * 128;

  const int srow = t >> 2, scol = (t & 3) * 8;
  const u16* gA = Ab + ((size_t)(rowBase + srow)) * K + scol;
  const u16* gB = Bb + ((size_t)(colBase + srow)) * K + scol;
  const size_t rstep = (size_t)64 * K;

  const int lr = lane & 15, lk = (lane >> 4) * 8;
  const u16* aRd = As + (wm * 64 + lr) * 32 + lk;
  const u16* bRd = Bs + (wn * 64 + lr) * 32 + lk;

  f32x4 acc[4][4] = {};
  const int nk = K >> 5;
  for (int kt = 0; kt < nk; ++kt) {
    __syncthreads();
    const int k0 = kt * 32;
    GL2LDS(gA + k0, As + t * 8);
    GL2LDS(gA + rstep + k0, As + 2048 + t * 8);
    GL2LDS(gB + k0, Bs + t * 8);
    GL2LDS(gB + rstep + k0, Bs + 2048 + t * 8);
    __syncthreads();
    u16x8 af[4], bfr[4];
#pragma unroll
    for (int i = 0; i < 4; ++i)
      af[i] = *reinterpret_cast<const u16x8*>(aRd + i * 16 * 32);
#pragma unroll
    for (int j = 0; j < 4; ++j)
      bfr[j] = *reinterpret_cast<const u16x8*>(bRd + j * 16 * 32);
#pragma unroll
    for (int i = 0; i < 4; ++i)
#pragma unroll
      for (int j = 0; j < 4; ++j)
        acc[i][j] = mfma_bf16(af[i], bfr[j], acc[i][j]);
  }

  const int lrow4 = (lane >> 4) * 4;
  const int lcol = lane & 15;
  if (MODE == 0 || MODE == 1) {
    float bias[4];
#pragma unroll
    for (int j = 0; j < 4; ++j) bias[j] = aux[colBase + wn * 64 + j * 16 + lcol];
    u16* out16 = (u16*)outp;
#pragma unroll
    for (int i = 0; i < 4; ++i) {
#pragma unroll
      for (int jj = 0; jj < 4; ++jj) {
        int r = rowBase + wm * 64 + i * 16 + lrow4 + jj;
#pragma unroll
        for (int j = 0; j < 4; ++j) {
          int c = colBase + wn * 64 + j * 16 + lcol;
          float v = acc[i][j][jj] + bias[j];
          if (MODE == 0) {
            out16[(size_t)r * N + c] = f2bf(v);
          } else {
            int b = r >> 11, s = r & (S_ - 1);
            out16[(size_t)b * D_ * S_ + (size_t)c * S_ + s] = f2bf(v);
          }
        }
      }
    }
  } else {
    float* outf = (float*)outp + (size_t)z * S_ * D_;
    const float* Zb = aux + (size_t)z * S_;
#pragma unroll
    for (int i = 0; i < 4; ++i) {
#pragma unroll
      for (int jj = 0; jj < 4; ++jj) {
        int r = rowBase + wm * 64 + i * 16 + lrow4 + jj;
        float rz = 1.0f / Zb[r];
#pragma unroll
        for (int j = 0; j < 4; ++j) {
          int c = colBase + wn * 64 + j * 16 + lcol;
          outf[(size_t)r * N + c] = acc[i][j][jj] * rz;
        }
      }
    }
  }
}

// ---------------------------------------------------------------- scores kernel
// For (b, q-tile of 128, k-split of 512 cols): logits = q @ k^T / 32;
// hyb = exp(l) * rot^2 * rinv (bf16, unnormalized); Z[b,row] += sum_k exp(l).
__global__ __launch_bounds__(256)
void score_kernel(const u16* __restrict__ qb, const u16* __restrict__ kb,
                  const float* __restrict__ rot, const float* __restrict__ rinv,
                  u16* __restrict__ hyb, float* __restrict__ Z) {
  __shared__ alignas(16) u16 As[4096];
  __shared__ alignas(16) u16 Bs[4096];
  const int t = threadIdx.x;
  const int lane = t & 63, w = t >> 6;
  const int wm = w >> 1, wn = w & 1;
  const int ks = blockIdx.x, qt = blockIdx.y, b = blockIdx.z;
  const int q0 = qt * 128;

  const int srow = t >> 2, scol = (t & 3) * 8;
  const u16* gA = qb + ((size_t)(b * S_ + q0 + srow)) * D_ + scol;
  const size_t rstep = (size_t)64 * D_;

  const int lr = lane & 15, lk = (lane >> 4) * 8;
  const u16* aRd = As + (wm * 64 + lr) * 32 + lk;
  const u16* bRd = Bs + (wn * 64 + lr) * 32 + lk;
  const int lrow4 = (lane >> 4) * 4;
  const int lcol = lane & 15;

  // hoist per-row rinv
  float rin[4][4];
#pragma unroll
  for (int i = 0; i < 4; ++i)
#pragma unroll
    for (int jj = 0; jj < 4; ++jj)
      rin[i][jj] = rinv[q0 + wm * 64 + i * 16 + lrow4 + jj];

  float zacc[4][4] = {};

  for (int t2 = 0; t2 < 4; ++t2) {
    const int kc0 = ks * 512 + t2 * 128;
    const u16* gB = kb + ((size_t)(b * S_ + kc0 + srow)) * D_ + scol;
    f32x4 acc[4][4] = {};
    for (int kt = 0; kt < 32; ++kt) {
      __syncthreads();
      const int k0 = kt * 32;
      GL2LDS(gA + k0, As + t * 8);
      GL2LDS(gA + rstep + k0, As + 2048 + t * 8);
      GL2LDS(gB + k0, Bs + t * 8);
      GL2LDS(gB + rstep + k0, Bs + 2048 + t * 8);
      __syncthreads();
      u16x8 af[4], bfr[4];
#pragma unroll
      for (int i = 0; i < 4; ++i)
        af[i] = *reinterpret_cast<const u16x8*>(aRd + i * 16 * 32);
#pragma unroll
      for (int j = 0; j < 4; ++j)
        bfr[j] = *reinterpret_cast<const u16x8*>(bRd + j * 16 * 32);
#pragma unroll
      for (int i = 0; i < 4; ++i)
#pragma unroll
        for (int j = 0; j < 4; ++j)
          acc[i][j] = mfma_bf16(af[i], bfr[j], acc[i][j]);
    }
    // epilogue for this 128x128 logits tile
#pragma unroll
    for (int i = 0; i < 4; ++i) {
#pragma unroll
      for (int jj = 0; jj < 4; ++jj) {
        const int row = q0 + wm * 64 + i * 16 + lrow4 + jj;
        const size_t hrow = ((size_t)(b * S_ + row)) * S_;
        const size_t rrow = (size_t)row * S_;
        const float ri = rin[i][jj];
#pragma unroll
        for (int j = 0; j < 4; ++j) {
          const int col = kc0 + wn * 64 + j * 16 + lcol;
          float e = __expf(acc[i][j][jj] * 0.03125f);
          float rv = rot[rrow + col];
          hyb[hrow + col] = f2bf(e * rv * rv * ri);
          zacc[i][jj] += e;
        }
      }
    }
  }

  // reduce Z across the 16 column-lanes, then atomically accumulate per row
#pragma unroll
  for (int i = 0; i < 4; ++i)
#pragma unroll
    for (int jj = 0; jj < 4; ++jj) {
      float v = zacc[i][jj];
#pragma unroll
      for (int d = 1; d < 16; d <<= 1) v += __shfl_xor(v, d);
      if ((lane & 15) == 0) {
        int row = q0 + wm * 64 + i * 16 + lrow4 + jj;
        atomicAdd(&Z[b * S_ + row], v);
      }
    }
}

// ---------------------------------------------------------------- launch
extern "C" void kernel_launch(void* const* d_in, const int* in_sizes, int n_in,
                              void* d_out, int out_size, void* d_ws, size_t ws_size,
                              hipStream_t stream) {
  const float* x = (const float*)d_in[0];
  const float* Wq = (const float*)d_in[1];
  const float* bq = (const float*)d_in[2];
  const float* Wk = (const float*)d_in[3];
  const float* bk = (const float*)d_in[4];
  const float* Wv = (const float*)d_in[5];
  const float* bv = (const float*)d_in[6];
  const float* rot = (const float*)d_in[7];

  char* ws = (char*)d_ws;
  size_t off = 0;
  auto take = [&](size_t bytes) {
    char* p = ws + off;
    off += (bytes + 255) & ~(size_t)255;
    return p;
  };
  u16* xb = (u16*)take((size_t)BN_ * S_ * D_ * 2);        // 32 MB
  u16* wqb = (u16*)take((size_t)D_ * D_ * 2);             // 2 MB
  u16* wkb = (u16*)take((size_t)D_ * D_ * 2);
  u16* wvb = (u16*)take((size_t)D_ * D_ * 2);
  u16* qb = (u16*)take((size_t)BN_ * S_ * D_ * 2);        // 32 MB
  u16* kb = (u16*)take((size_t)BN_ * S_ * D_ * 2);        // 32 MB
  u16* vtb = (u16*)take((size_t)BN_ * S_ * D_ * 2);       // 32 MB (B,D,S)
  u16* hyb = (u16*)take((size_t)BN_ * S_ * S_ * 2);       // 64 MB
  float* Zb = (float*)take((size_t)BN_ * S_ * 4);
  float* rinv = (float*)take((size_t)S_ * 4);

  hipMemsetAsync(Zb, 0, (size_t)BN_ * S_ * 4, stream);

  cvt_bf16<<<2048, 256, 0, stream>>>(x, xb, BN_ * S_ * D_ / 8);
  cvt_bf16<<<512, 256, 0, stream>>>(Wq, wqb, D_ * D_ / 8);
  cvt_bf16<<<512, 256, 0, stream>>>(Wk, wkb, D_ * D_ / 8);
  cvt_bf16<<<512, 256, 0, stream>>>(Wv, wvb, D_ * D_ / 8);
  rownorm_kernel<<<S_, 256, 0, stream>>>(rot, rinv);

  const int M = BN_ * S_;  // 16384
  gemm_bt<0><<<dim3(D_ / 128, M / 128, 1), 256, 0, stream>>>(xb, wqb, bq, qb, M, D_, D_);
  gemm_bt<0><<<dim3(D_ / 128, M / 128, 1), 256, 0, stream>>>(xb, wkb, bk, kb, M, D_, D_);
  gemm_bt<1><<<dim3(D_ / 128, M / 128, 1), 256, 0, stream>>>(xb, wvb, bv, vtb, M, D_, D_);

  score_kernel<<<dim3(4, S_ / 128, BN_), 256, 0, stream>>>(qb, kb, rot, rinv, hyb, Zb);

  gemm_bt<2><<<dim3(D_ / 128, S_ / 128, BN_), 256, 0, stream>>>(hyb, vtb, Zb, d_out,
                                                                S_, D_, S_);
}